// Round 3
// baseline (569.487 us; speedup 1.0000x reference)
//
#include <hip/hip_runtime.h>
#include <hip/hip_bf16.h>

typedef __attribute__((ext_vector_type(8))) short bf16x8;
typedef __attribute__((ext_vector_type(4))) float f32x4;

#define HID    128
#define KDIM   256   // 2*HID
#define MT     64    // edges per block

__device__ __forceinline__ unsigned short f2bf(float x) {
    unsigned int u = __float_as_uint(x);
    u += 0x7FFFu + ((u >> 16) & 1u);      // round-to-nearest-even
    return (unsigned short)(u >> 16);
}

__device__ __forceinline__ int pack2(float a, float b) {
    return (int)f2bf(a) | ((int)f2bf(b) << 16);
}

// ---- fp32 -> bf16 conversion for W1, W2 only (vec4) ----
__global__ void convert_w_kernel(const float* __restrict__ W1,
                                 const float* __restrict__ W2,
                                 unsigned short* __restrict__ w1b,
                                 unsigned short* __restrict__ w2b,
                                 int nw14, int nw24) {
    int i = blockIdx.x * blockDim.x + threadIdx.x;
    if (i >= nw14 + nw24) return;
    const float4* src;
    unsigned short* dst;
    int j;
    if (i < nw14) { src = (const float4*)W1; dst = w1b; j = i; }
    else          { src = (const float4*)W2; dst = w2b; j = i - nw14; }
    float4 v = src[j];
    ushort4 o;
    o.x = f2bf(v.x); o.y = f2bf(v.y); o.z = f2bf(v.z); o.w = f2bf(v.w);
    *(ushort4*)(dst + (size_t)j * 4) = o;
}

// ---- fused gather + 3-layer MLP ----
// LDS: A-tile [64][256] bf16 swizzled (32 KB) | h1 [64][256] bf16 swizzled (32 KB)
//      h2 [64][65] f32 aliases A-tile after layer 1 (barrier-protected).
__global__ __launch_bounds__(256, 2)
void disc_kernel(const float* __restrict__ z,
                 const int* __restrict__ ei,         // int32 per harness contract
                 const unsigned short* __restrict__ w1b,
                 const float* __restrict__ b1,
                 const unsigned short* __restrict__ w2b,
                 const float* __restrict__ b2,
                 const float* __restrict__ W3,
                 const float* __restrict__ b3,
                 float* __restrict__ out, int E) {
    __shared__ __align__(16) unsigned char smem[65536];
    unsigned char* Abuf  = smem;          // 32 KB
    unsigned char* H1buf = smem + 32768;  // 32 KB

    const int tid  = threadIdx.x;
    const int wave = tid >> 6;
    const int lane = tid & 63;
    const int lr   = lane & 15;   // row-sel (A) / col-sel (B, D)
    const int lk   = lane >> 4;   // k-group
    const int e0   = blockIdx.x * MT;

    // ---- gather + f32->bf16: 4 threads per edge ----
    {
        int r = tid >> 2, q = tid & 3;
        int e = e0 + r;
        if (e >= E) e = E - 1;
        int s = ei[e];
        int d = ei[E + e];
        const float4* zs = (const float4*)(z + (size_t)s * HID);
        const float4* zd = (const float4*)(z + (size_t)d * HID);
        const int swz = (r & 7) << 4;
        #pragma unroll
        for (int j = 0; j < 8; ++j) {
            int c = q * 8 + j;                       // out 16B chunk, 8 bf16 elems
            const float4* src = (c < 16) ? (zs + c * 2) : (zd + (c - 16) * 2);
            float4 v0 = src[0];
            float4 v1 = src[1];
            int4 o;
            o.x = pack2(v0.x, v0.y);
            o.y = pack2(v0.z, v0.w);
            o.z = pack2(v1.x, v1.y);
            o.w = pack2(v1.z, v1.w);
            *(int4*)(Abuf + r * 512 + ((c * 16) ^ swz)) = o;
        }
    }
    __syncthreads();

    // ---- layer 1: [64 x 256] = A[64 x 256] @ W1^T, wave owns 64 cols ----
    f32x4 acc[4][4];
    #pragma unroll
    for (int mi = 0; mi < 4; ++mi)
        #pragma unroll
        for (int ni = 0; ni < 4; ++ni)
            acc[mi][ni] = (f32x4){0.f, 0.f, 0.f, 0.f};

    const int n0 = wave * 64;
    #pragma unroll
    for (int ks = 0; ks < 8; ++ks) {
        const int kb = ks * 64 + lk * 16;  // byte offset of k within a row
        bf16x8 a[4], b[4];
        #pragma unroll
        for (int mi = 0; mi < 4; ++mi) {
            int row = mi * 16 + lr;
            a[mi] = *(const bf16x8*)(Abuf + row * 512 + (kb ^ ((row & 7) << 4)));
        }
        #pragma unroll
        for (int ni = 0; ni < 4; ++ni) {
            int col = n0 + ni * 16 + lr;
            b[ni] = *(const bf16x8*)(w1b + (size_t)col * KDIM + ks * 32 + lk * 8);
        }
        #pragma unroll
        for (int mi = 0; mi < 4; ++mi)
            #pragma unroll
            for (int ni = 0; ni < 4; ++ni)
                acc[mi][ni] = __builtin_amdgcn_mfma_f32_16x16x32_bf16(
                    a[mi], b[ni], acc[mi][ni], 0, 0, 0);
    }

    // epilogue: bias + leaky -> h1 (bf16, swizzled)
    #pragma unroll
    for (int ni = 0; ni < 4; ++ni) {
        int col = n0 + ni * 16 + lr;
        float bias = b1[col];
        #pragma unroll
        for (int mi = 0; mi < 4; ++mi) {
            #pragma unroll
            for (int rg = 0; rg < 4; ++rg) {
                int row = mi * 16 + lk * 4 + rg;
                float x = acc[mi][ni][rg] + bias;
                x = x > 0.f ? x : 0.2f * x;
                *(unsigned short*)(H1buf + row * 512 + ((col * 2) ^ ((row & 7) << 4))) = f2bf(x);
            }
        }
    }
    __syncthreads();

    // ---- layer 2: [64 x 64] = h1 @ W2^T, wave owns 16 cols ----
    f32x4 acc2[4];
    #pragma unroll
    for (int mi = 0; mi < 4; ++mi) acc2[mi] = (f32x4){0.f, 0.f, 0.f, 0.f};
    const int c2 = wave * 16 + lr;
    #pragma unroll
    for (int ks = 0; ks < 8; ++ks) {
        const int kb = ks * 64 + lk * 16;
        bf16x8 a[4];
        #pragma unroll
        for (int mi = 0; mi < 4; ++mi) {
            int row = mi * 16 + lr;
            a[mi] = *(const bf16x8*)(H1buf + row * 512 + (kb ^ ((row & 7) << 4)));
        }
        bf16x8 b = *(const bf16x8*)(w2b + (size_t)c2 * KDIM + ks * 32 + lk * 8);
        #pragma unroll
        for (int mi = 0; mi < 4; ++mi)
            acc2[mi] = __builtin_amdgcn_mfma_f32_16x16x32_bf16(a[mi], b, acc2[mi], 0, 0, 0);
    }

    // epilogue: bias + leaky -> h2 fp32 [64][65] (aliases A-tile; safe after barrier)
    float* h2 = (float*)Abuf;
    {
        float bias2 = b2[c2];
        #pragma unroll
        for (int mi = 0; mi < 4; ++mi) {
            #pragma unroll
            for (int rg = 0; rg < 4; ++rg) {
                int row = mi * 16 + lk * 4 + rg;
                float x = acc2[mi][rg] + bias2;
                x = x > 0.f ? x : 0.2f * x;
                h2[row * 65 + c2] = x;
            }
        }
    }
    __syncthreads();

    // ---- layer 3: out[r] = h2[r][:] . W3 + b3 ----
    {
        int r = tid >> 2, part = tid & 3;
        float s = 0.f;
        #pragma unroll
        for (int j = 0; j < 16; ++j) {
            int c = part * 16 + j;
            s += h2[r * 65 + c] * W3[c];
        }
        s += __shfl_xor(s, 1);
        s += __shfl_xor(s, 2);
        int e = e0 + r;
        if (part == 0 && e < E) out[e] = s + b3[0];
    }
}

extern "C" void kernel_launch(void* const* d_in, const int* in_sizes, int n_in,
                              void* d_out, int out_size, void* d_ws, size_t ws_size,
                              hipStream_t stream) {
    const float* z  = (const float*)d_in[0];
    const int*   ei = (const int*)d_in[1];       // int32 per harness contract
    const float* W1 = (const float*)d_in[2];
    const float* b1 = (const float*)d_in[3];
    const float* W2 = (const float*)d_in[4];
    const float* b2 = (const float*)d_in[5];
    const float* W3 = (const float*)d_in[6];
    const float* b3 = (const float*)d_in[7];
    float* out = (float*)d_out;

    const int E   = in_sizes[1] / 2;   // 1,000,000
    const int nw1 = in_sizes[2];       // 65,536
    const int nw2 = in_sizes[4];       // 16,384

    unsigned short* w1b = (unsigned short*)d_ws;          // 128 KB
    unsigned short* w2b = w1b + nw1;                      // +32 KB

    const int ntot = (nw1 + nw2) / 4;
    convert_w_kernel<<<(ntot + 255) / 256, 256, 0, stream>>>(W1, W2, w1b, w2b,
                                                             nw1 / 4, nw2 / 4);

    const int blocks = (E + MT - 1) / MT;   // 15625
    disc_kernel<<<blocks, 256, 0, stream>>>(z, ei, w1b, b1, w2b, b2, W3, b3, out, E);
}